// Round 8
// baseline (217.534 us; speedup 1.0000x reference)
//
#include <hip/hip_runtime.h>

// GradientLoss: g(x) = sqrt(gv^2 + gh^2 + eps), loss = mean(|g(in) - g(tgt)|)
// gv[h][w] = x[h+1][w] - x[h-1][w]  (zero pad), gh[h][w] = x[h][w+1] - x[h][w-1]
// Shapes: (32, 3, 512, 512) fp32 -> 96 planes of 512x512. Output: 1 fp32.
//
// Max-TLP streaming form: 2048 blocks x 256 threads grid-stride (8192 waves,
// enough to fill 8 waves/SIMD chip-wide). Thread-iter = one 8-float segment
// (2x float4) of one row, both tensors. Branchless: vertical/horizontal
// halos via clamped-address loads (v_cndmask offsets, always in-bounds) and
// 0/1 float masks. Raw v_sqrt_f32. ~16 load instrs + ~140 VALU per iter.
// L1/L2 absorb the 3x row reuse; HBM stays at the 201 MB compulsory floor.

constexpr int H = 512, W = 512;
constexpr int PLANES = 96;                // N*C = 32*3
constexpr int SEGS = W / 8;               // 64 segments per row
constexpr int TOTAL = PLANES * H * SEGS;  // 3,145,728 segment-positions
constexpr int NBLOCKS = 2048;             // x256 thr -> 6 iters/thread exact
constexpr float EPS = 1e-6f;
constexpr float INV_N = 1.0f / ((float)PLANES * (float)H * (float)W);

// gradient magnitude for 8 contiguous pixels (cols c0..c0+7 of row h)
__device__ __forceinline__ void seg_grad(
    const float* __restrict__ x, int base,
    int upo, int dno, int lfo, int rto,
    float mu, float md, float ml, float mr,
    float g[8])
{
    const float4 cA = *reinterpret_cast<const float4*>(x + base);
    const float4 cB = *reinterpret_cast<const float4*>(x + base + 4);
    const float4 uA = *reinterpret_cast<const float4*>(x + base + upo);
    const float4 uB = *reinterpret_cast<const float4*>(x + base + upo + 4);
    const float4 dA = *reinterpret_cast<const float4*>(x + base + dno);
    const float4 dB = *reinterpret_cast<const float4*>(x + base + dno + 4);
    const float2 lf = *reinterpret_cast<const float2*>(x + base + lfo); // .y = col c0-1
    const float2 rt = *reinterpret_cast<const float2*>(x + base + rto); // .x = col c0+8

    const float c[8] = {cA.x, cA.y, cA.z, cA.w, cB.x, cB.y, cB.z, cB.w};
    const float u[8] = {uA.x, uA.y, uA.z, uA.w, uB.x, uB.y, uB.z, uB.w};
    const float d[8] = {dA.x, dA.y, dA.z, dA.w, dB.x, dB.y, dB.z, dB.w};

    float gh[8];
    gh[0] = c[1] - lf.y * ml;
    #pragma unroll
    for (int i = 1; i < 7; ++i) gh[i] = c[i + 1] - c[i - 1];
    gh[7] = rt.x * mr - c[6];

    #pragma unroll
    for (int i = 0; i < 8; ++i) {
        const float gv = d[i] * md - u[i] * mu;
        g[i] = __builtin_amdgcn_sqrtf(fmaf(gv, gv, fmaf(gh[i], gh[i], EPS)));
    }
}

__global__ __launch_bounds__(256) void grad_loss_kernel(
    const float* __restrict__ src0,
    const float* __restrict__ src1,
    float* __restrict__ out)
{
    float acc = 0.f;
    const int stride = gridDim.x * blockDim.x;   // 524,288

    for (int idx = blockIdx.x * blockDim.x + threadIdx.x;
         idx < TOTAL; idx += stride) {

        const int seg   = idx & 63;              // segment in row
        const int h     = (idx >> 6) & 511;      // row
        const int plane = idx >> 15;             // plane
        const int c0    = seg << 3;
        const int base  = (plane << 18) + (h << 9) + c0;

        // clamped halo offsets (always valid addresses) + 0/1 masks
        const int   upo = (h > 0)       ? -W : 0;
        const int   dno = (h < H - 1)   ?  W : 0;
        const int   lfo = (c0 > 0)      ? -2 : 0;
        const int   rto = (c0 + 8 < W)  ?  8 : 0;
        const float mu  = (h > 0)       ? 1.f : 0.f;
        const float md  = (h < H - 1)   ? 1.f : 0.f;
        const float ml  = (c0 > 0)      ? 1.f : 0.f;
        const float mr  = (c0 + 8 < W)  ? 1.f : 0.f;

        float gi[8], gt[8];
        seg_grad(src0, base, upo, dno, lfo, rto, mu, md, ml, mr, gi);
        seg_grad(src1, base, upo, dno, lfo, rto, mu, md, ml, mr, gt);

        #pragma unroll
        for (int i = 0; i < 8; ++i) acc += fabsf(gi[i] - gt[i]);
    }

    // ---- wave reduction (64 lanes) ----
    #pragma unroll
    for (int off = 32; off > 0; off >>= 1)
        acc += __shfl_down(acc, off, 64);

    __shared__ float wsum[4];
    const int lane = threadIdx.x & 63;
    const int wv   = threadIdx.x >> 6;
    if (lane == 0) wsum[wv] = acc;
    __syncthreads();

    if (threadIdx.x == 0) {
        const float s = wsum[0] + wsum[1] + wsum[2] + wsum[3];
        atomicAdd(out, s * INV_N);
    }
}

extern "C" void kernel_launch(void* const* d_in, const int* in_sizes, int n_in,
                              void* d_out, int out_size, void* d_ws, size_t ws_size,
                              hipStream_t stream) {
    const float* in  = (const float*)d_in[0];
    const float* tgt = (const float*)d_in[1];
    float* out = (float*)d_out;

    // d_out is poisoned with 0xAA before every launch — zero it first.
    hipMemsetAsync(out, 0, sizeof(float), stream);

    grad_loss_kernel<<<NBLOCKS, 256, 0, stream>>>(in, tgt, out);
}

// Round 9
// 213.107 us; speedup vs baseline: 1.0208x; 1.0208x over previous
//
#include <hip/hip_runtime.h>

// GradientLoss: g(x) = sqrt(gv^2 + gh^2 + eps), loss = mean(|g(in) - g(tgt)|)
// gv[h][w] = x[h+1][w] - x[h-1][w]  (zero pad), gh[h][w] = x[h][w+1] - x[h][w-1]
// Shapes: (32, 3, 512, 512) fp32 -> 96 planes of 512x512. Output: 1 fp32.
//
// Column-march (byte-minimal): wave = 256-col x 16-row chunk. Lane owns 4
// columns -> ONE dwordx4 per row per tensor (the exact access shape of the
// 6.3 TB/s copy ubench). Vertical neighbors from a 4-slot rolling register
// window: every byte passes through L1 exactly once (+2/16 rows chunk halo).
// Horizontal neighbors via shfl; strip seam & plane edges via 2 uniform-
// address broadcast dword loads + 0/1 masks (no divergent branches).
// 6144 waves, ~8 VALU per output pixel.

constexpr int H = 512, W = 512;
constexpr int PLANES = 96;               // N*C = 32*3
constexpr int RCHUNK = 16;               // rows per wave
constexpr int CHUNKS = H / RCHUNK;       // 32
constexpr int WPB = 4;                   // waves per block
constexpr int NWAVES = PLANES * 2 * CHUNKS;   // 6144
constexpr int NBLOCKS = NWAVES / WPB;         // 1536
constexpr float EPS = 1e-6f;
constexpr float INV_N = 1.0f / ((float)PLANES * (float)H * (float)W);

struct Slot { float4 m; float hl, hr; };   // main 4 cols + 2 halo cols

__global__ __launch_bounds__(256) void grad_loss_kernel(
    const float* __restrict__ s0,
    const float* __restrict__ s1,
    float* __restrict__ out)
{
    const int tid  = threadIdx.x;
    const int lane = tid & 63;
    const int wv   = tid >> 6;
    const int wid  = blockIdx.x * WPB + wv;
    const int plane = wid >> 6;            // 64 wave-slots per plane
    const int rem   = wid & 63;
    const int strip = rem & 1;             // 0: cols 0-255, 1: cols 256-511
    const int chunk = rem >> 1;
    const int h0    = chunk * RCHUNK;
    const int cbase = strip << 8;

    const int pb  = plane * (H * W) + h0 * W;   // row h0 of this plane
    const int mc  = cbase + (lane << 2);        // lane's 4 columns
    const int hlc = strip ? cbase - 1 : 0;      // left-halo col (clamped)
    const int hrc = strip ? W - 1 : cbase + 256;// right-halo col (clamped)
    const float ml = strip ? 1.f : 0.f;         // left neighbor exists?
    const float mr = strip ? 0.f : 1.f;         // right neighbor exists?

    const bool firstChunk = (h0 == 0);          // wave-uniform
    const bool lastChunk  = (h0 + RCHUNK == H); // wave-uniform

    const float* gs[2] = { s0, s1 };
    Slot sl[2][4];                              // 4-slot rolling window

#define LD(t, r, s)                                                          \
    {   const float* p = gs[t] + pb + (r) * W;                               \
        sl[t][s].m  = *reinterpret_cast<const float4*>(p + mc);              \
        sl[t][s].hl = p[hlc];                                                \
        sl[t][s].hr = p[hrc]; }
#define ZR(t, s)                                                             \
    {   sl[t][s].m = make_float4(0.f, 0.f, 0.f, 0.f);                        \
        sl[t][s].hl = 0.f; sl[t][s].hr = 0.f; }

    // prologue: rows h0-1, h0, h0+1 -> slots 0,1,2
    #pragma unroll
    for (int t = 0; t < 2; ++t) {
        if (firstChunk) { ZR(t, 0) } else { LD(t, -1, 0) }
        LD(t, 0, 1)
        LD(t, 1, 2)
    }

    float acc = 0.f;

    #pragma unroll
    for (int k = 0; k < RCHUNK; ++k) {
        // prefetch row h0+k+2 into slot (k+3)&3 (rows 2..16; 16 = halo)
        if (k <= RCHUNK - 2) {
            #pragma unroll
            for (int t = 0; t < 2; ++t) {
                if (k == RCHUNK - 2 && lastChunk) { ZR(t, (k + 3) & 3) }
                else                              { LD(t, k + 2, (k + 3) & 3) }
            }
        }

        float g[2][4];
        #pragma unroll
        for (int t = 0; t < 2; ++t) {
            const Slot& up = sl[t][ k      & 3];
            const Slot& cu = sl[t][(k + 1) & 3];
            const Slot& dn = sl[t][(k + 2) & 3];

            const float lws = __shfl_up  (cu.m.w, 1, 64);
            const float rws = __shfl_down(cu.m.x, 1, 64);
            const float lw = (lane == 0)  ? cu.hl * ml : lws;
            const float rw = (lane == 63) ? cu.hr * mr : rws;

            const float gh0 = cu.m.y - lw;
            const float gh1 = cu.m.z - cu.m.x;
            const float gh2 = cu.m.w - cu.m.y;
            const float gh3 = rw     - cu.m.z;

            const float gv0 = dn.m.x - up.m.x;
            const float gv1 = dn.m.y - up.m.y;
            const float gv2 = dn.m.z - up.m.z;
            const float gv3 = dn.m.w - up.m.w;

            g[t][0] = __builtin_amdgcn_sqrtf(fmaf(gv0, gv0, fmaf(gh0, gh0, EPS)));
            g[t][1] = __builtin_amdgcn_sqrtf(fmaf(gv1, gv1, fmaf(gh1, gh1, EPS)));
            g[t][2] = __builtin_amdgcn_sqrtf(fmaf(gv2, gv2, fmaf(gh2, gh2, EPS)));
            g[t][3] = __builtin_amdgcn_sqrtf(fmaf(gv3, gv3, fmaf(gh3, gh3, EPS)));
        }

        acc += fabsf(g[0][0] - g[1][0]) + fabsf(g[0][1] - g[1][1])
             + fabsf(g[0][2] - g[1][2]) + fabsf(g[0][3] - g[1][3]);
    }
#undef LD
#undef ZR

    // ---- wave reduction (64 lanes) ----
    #pragma unroll
    for (int off = 32; off > 0; off >>= 1)
        acc += __shfl_down(acc, off, 64);

    __shared__ float wsum[WPB];
    if (lane == 0) wsum[wv] = acc;
    __syncthreads();

    if (tid == 0) {
        const float s = wsum[0] + wsum[1] + wsum[2] + wsum[3];
        atomicAdd(out, s * INV_N);
    }
}

extern "C" void kernel_launch(void* const* d_in, const int* in_sizes, int n_in,
                              void* d_out, int out_size, void* d_ws, size_t ws_size,
                              hipStream_t stream) {
    const float* in  = (const float*)d_in[0];
    const float* tgt = (const float*)d_in[1];
    float* out = (float*)d_out;

    // d_out is poisoned with 0xAA before every launch — zero it first.
    hipMemsetAsync(out, 0, sizeof(float), stream);

    grad_loss_kernel<<<NBLOCKS, 64 * WPB, 0, stream>>>(in, tgt, out);
}